// Round 11
// baseline (17.455 us; speedup 1.0000x reference)
//
#include <hip/hip_runtime.h>

#define BB 8
#define HH 256
#define WW 256
#define BHW (BB*HH*WW)

// ws layout:
//   [0, 128KB) u64    : colmask[img(16)][col(256)][word(4)] — column threshold
//                       bitmask, bit r of word w = row 64w+r (img = ip*8+b)
//   then 256 ints     : per-mask_build-block any-fg flags (slot = blockIdx)
//   then BB*HH floats : per-row partial sums

// kernel1: threshold -> column bitmasks (128KB). Same proven load pattern as
// the R6 edt_vert, but NO distance math and a 16x smaller store.
__global__ __launch_bounds__(256) void mask_build(const float* __restrict__ x,
                                                  const float* __restrict__ y,
                                                  unsigned long long* __restrict__ colmask,
                                                  int* __restrict__ blkflag) {
    __shared__ unsigned short lm[16][16];   // [seg][col-in-tile]
    __shared__ int sAny;
    int blk = blockIdx.x;
    int tileIdx = blk & 15;
    int b  = (blk >> 4) & 7;
    int ip = blk >> 7;
    int t = threadIdx.x;
    int c = t & 15, s = t >> 4;

    if (t == 0) sAny = 0;

    const float* src = (ip ? y : x) + (size_t)b*HH*WW + tileIdx*16 + c;
    unsigned m = 0;
    const float* p = src + (size_t)(s*16)*WW;
    #pragma unroll
    for (int i = 0; i < 16; ++i)
        if (p[(size_t)i*WW] > 0.5f) m |= (1u << i);
    lm[s][c] = (unsigned short)m;
    __syncthreads();
    if (m) sAny = 1;                        // benign LDS race

    if (t < 64) {                           // transpose: 4 u64 words per column
        int col = t >> 2, wsel = t & 3;
        unsigned long long w0 =  (unsigned long long)lm[4*wsel+0][col]
                              | ((unsigned long long)lm[4*wsel+1][col] << 16)
                              | ((unsigned long long)lm[4*wsel+2][col] << 32)
                              | ((unsigned long long)lm[4*wsel+3][col] << 48);
        int img = ip*8 + b;
        colmask[((size_t)img*256 + tileIdx*16 + col)*4 + wsel] = w0;
    }
    __syncthreads();
    if (t == 0) blkflag[blk] = sAny;        // own slot: no init needed
}

// Exact nearest-set-bit distance from uniform row h to the zero-set of the
// pixel's channel (Z = fg-pixel ? ~M : M), capped at 512. Monotone word
// distance => farthest-to-closest overwrite chain, no min tree.
__device__ __forceinline__ int vdist256(unsigned long long m0, unsigned long long m1,
                                        unsigned long long m2, unsigned long long m3,
                                        int w, int off,
                                        unsigned long long lowm, unsigned long long highm,
                                        bool& fgpix) {
    unsigned long long mw = (w==0) ? m0 : ((w==1) ? m1 : ((w==2) ? m2 : m3));
    fgpix = ((mw >> off) & 1ull) != 0ull;
    unsigned long long z0 = fgpix ? ~m0 : m0;
    unsigned long long z1 = fgpix ? ~m1 : m1;
    unsigned long long z2 = fgpix ? ~m2 : m2;
    unsigned long long z3 = fgpix ? ~m3 : m3;
    unsigned long long zw = fgpix ? ~mw : mw;
    unsigned long long tl = zw & lowm, th = zw & highm;

    int du = 1024;
    { bool val = (w > 0) && (z0 != 0ull); int d =  w   *64 + off - (63 - __clzll((long long)(z0|1ull))); du = val ? d : du; }
    { bool val = (w > 1) && (z1 != 0ull); int d = (w-1)*64 + off - (63 - __clzll((long long)(z1|1ull))); du = val ? d : du; }
    { bool val = (w > 2) && (z2 != 0ull); int d = (w-2)*64 + off - (63 - __clzll((long long)(z2|1ull))); du = val ? d : du; }
    { int d = off - (63 - __clzll((long long)(tl|1ull))); du = (tl != 0ull) ? d : du; }

    int dd = 1024;
    { bool val = (w < 3) && (z3 != 0ull); int d = (3-w)*64 + (__ffsll(z3) - 1) - off; dd = val ? d : dd; }
    { bool val = (w < 2) && (z2 != 0ull); int d = (2-w)*64 + (__ffsll(z2) - 1) - off; dd = val ? d : dd; }
    { bool val = (w < 1) && (z1 != 0ull); int d = (1-w)*64 + (__ffsll(z1) - 1) - off; dd = val ? d : dd; }
    { int d = (__ffsll(th) - 1) - off;    dd = (th != 0ull) ? d : dd; }

    int g = du < dd ? du : dd;
    return g > 512 ? 512 : g;               // cap matches reference BIG=H+W
}

// kernel2: R6 row_pass body, with the gdist load replaced by in-register
// vertical-distance computation from L2-hot column masks.
__global__ __launch_bounds__(256) void row_pass(const float* __restrict__ x,
                                                const float* __restrict__ y,
                                                const unsigned long long* __restrict__ colmask,
                                                const int* __restrict__ blkflag,
                                                float* __restrict__ partials) {
    __shared__ float sp0[768], sp1[768], sp2[768], sp3[768];
    __shared__ float wsum[4];
    __shared__ float sF[2];
    int bh = blockIdx.x;          // b*HH + h
    int b  = bh >> 8;
    int h  = bh & 255;
    int j  = threadIdx.x;
    size_t rowoff = (size_t)bh * WW;

    float xv = x[rowoff + j];
    float yv = y[rowoff + j];

    int w = h >> 6, off = h & 63;                       // wave-uniform
    unsigned long long lowm  = (off == 63) ? ~0ull : ((1ull << (off+1)) - 1ull);
    unsigned long long highm = ~((1ull << off) - 1ull);
    const ulonglong2* cmx = (const ulonglong2*)(colmask + ((size_t)b*256 + j)*4);
    const ulonglong2* cmy = (const ulonglong2*)(colmask + ((size_t)(8+b)*256 + j)*4);
    ulonglong2 qa = cmx[0], qb = cmx[1];                // x: m0..m3
    ulonglong2 qc = cmy[0], qd = cmy[1];                // y: m0..m3

    bool fgx, fgy;
    int gx = vdist256(qa.x, qa.y, qb.x, qb.y, w, off, lowm, highm, fgx);
    int gy = vdist256(qc.x, qc.y, qd.x, qd.y, w, off, lowm, highm, fgy);
    int gx2 = gx * gx, gy2 = gy * gy;                   // <= 512^2, exact in f32
    float v0 = fgx ? (float)gx2 : 0.0f;                 // x fg-EDT g^2
    float v1 = fgx ? 0.0f : (float)gx2;                 // x bg-EDT g^2
    float v2 = fgy ? (float)gy2 : 0.0f;                 // y fg-EDT g^2
    float v3 = fgy ? 0.0f : (float)gy2;                 // y bg-EDT g^2

    sp0[j] = 1e9f; sp1[j] = 1e9f; sp2[j] = 1e9f; sp3[j] = 1e9f;
    sp0[j+512] = 1e9f; sp1[j+512] = 1e9f; sp2[j+512] = 1e9f; sp3[j+512] = 1e9f;
    sp0[j+256] = v0; sp1[j+256] = v1; sp2[j+256] = v2; sp3[j+256] = v3;

    if (j < 64) {   // wave 0: gather has_fg flags (OR over 16 tile slots per input)
        int v = 0;
        if (j < 32) v = blkflag[((j < 16) ? 0 : 128) + b * 16 + (j & 15)];
        unsigned long long ball = __ballot(v != 0);
        if (j == 0) {
            sF[0] = (ball & 0xFFFFull) ? 1.0f : 0.0f;
            sF[1] = ((ball >> 16) & 0xFFFFull) ? 1.0f : 0.0f;
        }
    }
    __syncthreads();

    float b0 = v0, b1 = v1, b2 = v2, b3 = v3;
    for (int dl = 1; dl < 256; ++dl) {
        float d2 = (float)(dl * dl);
        float bmax = fmaxf(fmaxf(b0, b1), fmaxf(b2, b3));
        if (!__any(d2 < bmax)) break;     // no candidate can improve any lane in wave
        int l = j + 256 - dl, r = j + 256 + dl;
        b0 = fminf(b0, fminf(d2 + sp0[l], d2 + sp0[r]));
        b1 = fminf(b1, fminf(d2 + sp1[l], d2 + sp1[r]));
        b2 = fminf(b2, fminf(d2 + sp2[l], d2 + sp2[r]));
        b3 = fminf(b3, fminf(d2 + sp3[l], d2 + sp3[r]));
    }

    float dtx = sF[0] != 0.0f ? (sqrtf(b0) + sqrtf(b1)) : 0.0f;
    float dty = sF[1] != 0.0f ? (sqrtf(b2) + sqrtf(b3)) : 0.0f;
    float e = xv - yv;
    float val = e * e * (dtx * dtx + dty * dty);

    for (int off2 = 32; off2; off2 >>= 1) val += __shfl_down(val, off2, 64);
    if ((j & 63) == 0) wsum[j >> 6] = val;
    __syncthreads();
    if (j == 0) partials[bh] = wsum[0] + wsum[1] + wsum[2] + wsum[3];
}

__global__ __launch_bounds__(256) void final_reduce(const float* __restrict__ partials,
                                                    float* __restrict__ out) {
    __shared__ float wsum[4];
    int j = threadIdx.x;
    float s = 0.0f;
    #pragma unroll
    for (int i = 0; i < 8; ++i) s += partials[i * 256 + j];
    for (int off = 32; off; off >>= 1) s += __shfl_down(s, off, 64);
    if ((j & 63) == 0) wsum[j >> 6] = s;
    __syncthreads();
    if (j == 0) out[0] = (wsum[0] + wsum[1] + wsum[2] + wsum[3]) * (1.0f / (float)BHW);
}

extern "C" void kernel_launch(void* const* d_in, const int* in_sizes, int n_in,
                              void* d_out, int out_size, void* d_ws, size_t ws_size,
                              hipStream_t stream) {
    const float* x = (const float*)d_in[0];
    const float* y = (const float*)d_in[1];
    float* out = (float*)d_out;

    char* ws = (char*)d_ws;
    unsigned long long* colmask = (unsigned long long*)ws;                 // 16*256*4 u64 = 128KB
    int* blkflag = (int*)(ws + (size_t)16*256*4*sizeof(unsigned long long));
    float* partials = (float*)(ws + (size_t)16*256*4*sizeof(unsigned long long) + 256*sizeof(int));

    mask_build<<<256, 256, 0, stream>>>(x, y, colmask, blkflag);
    row_pass<<<BB * HH, 256, 0, stream>>>(x, y, colmask, blkflag, partials);
    final_reduce<<<1, 256, 0, stream>>>(partials, out);
}